// Round 16
// baseline (340.555 us; speedup 1.0000x reference)
//
#include <hip/hip_runtime.h>
#include <cmath>

// ---------------------------------------------------------------------------
// PointCloudFeatureExtractor — full pipeline port (fp32).
// Round 16: knn query constants pinned to SGPRs via readfirstlane (they are
//           block-uniform) -> frees ~32 VGPRs so the PF=4 prefetch pipeline
//           can actually allocate. Rest identical to R15.
// ---------------------------------------------------------------------------

__device__ __forceinline__ unsigned flipf(float f) {
    unsigned u = __float_as_uint(f);
    return (u & 0x80000000u) ? ~u : (u | 0x80000000u);
}
__device__ __forceinline__ float unflip(unsigned u) {
    unsigned r = (u & 0x80000000u) ? (u & 0x7fffffffu) : ~u;
    return __uint_as_float(r);
}
__device__ __forceinline__ unsigned umin2(unsigned a, unsigned b) {
    return a < b ? a : b;
}
// exact for block-uniform values (same bits in every lane)
__device__ __forceinline__ float uniform_f(float x) {
    return __uint_as_float(__builtin_amdgcn_readfirstlane(__float_as_uint(x)));
}

template <int VC>
__device__ __forceinline__ void load_vec(float* d, const float* p) {
    if constexpr (VC == 1) { d[0] = p[0]; }
    else if constexpr (VC == 2) { const float2 t = *(const float2*)p; d[0] = t.x; d[1] = t.y; }
    else { const float4 t = *(const float4*)p; d[0] = t.x; d[1] = t.y; d[2] = t.z; d[3] = t.w; }
}
template <int VC>
__device__ __forceinline__ void store_vec(float* p, const float* d) {
    if constexpr (VC == 1) { p[0] = d[0]; }
    else if constexpr (VC == 2) { float2 t; t.x = d[0]; t.y = d[1]; *(float2*)p = t; }
    else { float4 t; t.x = d[0]; t.y = d[1]; t.z = d[2]; t.w = d[3]; *(float4*)p = t; }
}

// vq[i] = {x, y, z, (x*x+y*y)+z*z}  (exact op order of the distance formula)
__global__ __launch_bounds__(256) void precompute_vq(
    const float* __restrict__ v, float4* __restrict__ vq, int n)
{
#pragma clang fp contract(off)
    const int i = blockIdx.x * 256 + threadIdx.x;
    if (i < n) {
        const float x = v[i * 3 + 0];
        const float y = v[i * 3 + 1];
        const float z = v[i * 3 + 2];
        float4 o; o.x = x; o.y = y; o.z = z; o.w = (x * x + y * y) + z * z;
        vq[i] = o;
    }
}

// kNN v14: QPB=8 queries/block, SGPR-pinned query constants, sampled pass-1
// single-pass estimator, PF-pipelined full pass-2 extraction, M>=SEL
// exactness check, register-cached final ranking, rank-then-fallback with
// fallback buffers aliasing bufq. Distances bit-identical to round-1.
template <int CPT, int SMP, int SEL, int EST, int QPB = 8, int CAPQ = 160>
__global__ __launch_bounds__(256, 4) void knn_select(
    const float4* __restrict__ vq, int vStride, int nRows,
    int* __restrict__ outIdx)
{
#pragma clang fp contract(off)
    const int tid  = threadIdx.x;
    const int bpb  = nRows / QPB;
    const int b    = blockIdx.x / bpb;
    const int row0 = (blockIdx.x % bpb) * QPB;
    const float4* vb = vq + (size_t)b * vStride;

    // block-uniform query constants -> SGPRs (readfirstlane is exact here)
    float nx[QPB], ny[QPB], nz[QPB], qw[QPB];
#pragma unroll
    for (int qq = 0; qq < QPB; ++qq) {
        const float4 p = vb[row0 + qq];
        nx[qq] = uniform_f(p.x * -2.0f);
        ny[qq] = uniform_f(p.y * -2.0f);
        nz[qq] = uniform_f(p.z * -2.0f);
        qw[qq] = uniform_f(p.w);
    }

    // ---- pass 1 (sampled): per-thread min per query over SMP candidates ----
    float mn[QPB];
#pragma unroll
    for (int qq = 0; qq < QPB; ++qq) mn[qq] = INFINITY;
#pragma unroll
    for (int s = 0; s < SMP; ++s) {
        const float4 c = vb[tid + (s << 8)];
#pragma unroll
        for (int qq = 0; qq < QPB; ++qq) {
            const float t0 = (nx[qq] * c.x + ny[qq] * c.y) + nz[qq] * c.z;
            const float dist = (t0 + c.w) + qw[qq];
            mn[qq] = fminf(mn[qq], dist);
        }
    }

    // shared pool: bufq (normal path) and fD/fJ (fallback) never live
    // simultaneously -> alias. POOLB >= both.
    constexpr int POOLB = (QPB * CAPQ * 8 > CPT * SEL * 6) ? QPB * CAPQ * 8
                                                           : CPT * SEL * 6;
    __shared__ unsigned hmin[QPB][256];
    __shared__ __align__(16) char poolmem[POOLB];
    __shared__ unsigned Ts[QPB];
    __shared__ int cnt[QPB];
    __shared__ unsigned T2_s;
    __shared__ int fcnt;
    typedef unsigned long long u64row[CAPQ];
    u64row* bufq = (u64row*)poolmem;

#pragma unroll
    for (int qq = 0; qq < QPB; ++qq) hmin[qq][tid] = flipf(mn[qq]);
    if (tid < QPB) { Ts[tid] = 0u; cnt[tid] = 0; }
    __syncthreads();

    // ---- estimator: group g (32 thr) builds 64 combined minima in-place,
    //      then ranks BOTH its values in one 64-read sweep.
    {
        const int g = tid >> 5, l = tid & 31;
#pragma unroll
        for (int hh = 0; hh < 2; ++hh) {
            const int i = l + hh * 32;
            unsigned cm = hmin[g][i];
            cm = umin2(cm, hmin[g][i + 64]);
            cm = umin2(cm, hmin[g][i + 128]);
            cm = umin2(cm, hmin[g][i + 192]);
            hmin[g][i] = cm;               // same-lane read->write; same-wave
        }
        const unsigned vv0 = hmin[g][l];
        const unsigned vv1 = hmin[g][l + 32];
        int r0 = 0, r1 = 0;
#pragma unroll 8
        for (int k = 0; k < 64; ++k) {
            const unsigned h = hmin[g][k];
            r0 += (h < vv0) ? 1 : 0;
            r1 += (h < vv1) ? 1 : 0;
        }
        if (r0 < EST) atomicMax(&Ts[g], vv0);
        if (r1 < EST) atomicMax(&Ts[g], vv1);
    }
    __syncthreads();

    float Tf[QPB];
#pragma unroll
    for (int qq = 0; qq < QPB; ++qq) Tf[qq] = uniform_f(unflip(Ts[qq]));

    // ---- pass 2 (full): PF-pipelined extraction ----
    {
        constexpr int PF = (CPT < 4) ? CPT : 4;
        float4 cbuf[PF];
#pragma unroll
        for (int p = 0; p < PF; ++p) cbuf[p] = vb[tid + (p << 8)];
        for (int s0 = 0; s0 < CPT; s0 += PF) {
            float4 cur[PF];
#pragma unroll
            for (int p = 0; p < PF; ++p) cur[p] = cbuf[p];
            if (s0 + PF < CPT) {
#pragma unroll
                for (int p = 0; p < PF; ++p)
                    cbuf[p] = vb[tid + ((s0 + PF + p) << 8)];
            }
#pragma unroll
            for (int p = 0; p < PF; ++p) {
                const int j = tid + ((s0 + p) << 8);
                const float4 c = cur[p];
#pragma unroll
                for (int qq = 0; qq < QPB; ++qq) {
                    const float t0 = (nx[qq] * c.x + ny[qq] * c.y) + nz[qq] * c.z;
                    const float dist = (t0 + c.w) + qw[qq];
                    if (dist <= Tf[qq]) {
                        const int p2 = atomicAdd(&cnt[qq], 1);
                        if (p2 < CAPQ)
                            bufq[qq][p2] =
                                (((unsigned long long)flipf(dist)) << 32)
                                | (unsigned)j;
                    }
                }
            }
        }
    }
    __syncthreads();

    // ---- normal ranking FIRST (register-cached; one bufq sweep) ----
    {
        const int g = tid >> 5, i = tid & 31;
        const int M = cnt[g];
        if (M >= SEL && M <= CAPQ) {
            constexpr int KMAX = (CAPQ + 31) / 32;
            unsigned long long myk[KMAX];
            int rr[KMAX];
#pragma unroll
            for (int t = 0; t < KMAX; ++t) {
                const int s2 = i + t * 32;
                myk[t] = (s2 < M) ? bufq[g][s2] : ~0ull;  // sentinel: rank>=SEL
                rr[t] = 0;
            }
            for (int i2 = 0; i2 < M; ++i2) {
                const unsigned long long k2 = bufq[g][i2];
#pragma unroll
                for (int t = 0; t < KMAX; ++t) rr[t] += (k2 < myk[t]) ? 1 : 0;
            }
#pragma unroll
            for (int t = 0; t < KMAX; ++t) {
                if (rr[t] >= 1 && rr[t] < SEL)
                    outIdx[(size_t)(b * nRows + row0 + g) * (SEL - 1) + (rr[t] - 1)]
                        = (int)(myk[t] & 0xffffffffu);
            }
        }
    }
    __syncthreads();

    // ---- rare provable fallback, serialized per bad query; reuses pool ----
    for (int qq = 0; qq < QPB; ++qq) {
        const int M = cnt[qq];
        if (M >= SEL && M <= CAPQ) continue;      // block-uniform
        unsigned* fD = (unsigned*)poolmem;
        unsigned short* fJ = (unsigned short*)(poolmem + CPT * SEL * 4);
        // recompute FULL per-thread min for this query (restores proof)
        {
            float fm = INFINITY;
#pragma unroll 2
            for (int s = 0; s < CPT; ++s) {
                const float4 c = vb[tid + (s << 8)];
                const float t0 = (nx[qq] * c.x + ny[qq] * c.y) + nz[qq] * c.z;
                const float dist = (t0 + c.w) + qw[qq];
                fm = fminf(fm, dist);
            }
            hmin[qq][tid] = flipf(fm);
        }
        if (tid == 0) { T2_s = 0u; fcnt = 0; }
        __syncthreads();
        {
            const unsigned vv = hmin[qq][tid];
            int r = 0;
            for (int k = 0; k < 256; ++k) r += (hmin[qq][k] < vv) ? 1 : 0;
            if (r < SEL) atomicMax(&T2_s, vv);    // >= SEL keys <= T2
        }
        __syncthreads();
        const float T2f = unflip(T2_s);
#pragma unroll 2
        for (int s = 0; s < CPT; ++s) {
            const int j = tid + (s << 8);
            const float4 c = vb[j];
            const float t0 = (nx[qq] * c.x + ny[qq] * c.y) + nz[qq] * c.z;
            const float dist = (t0 + c.w) + qw[qq];
            if (dist <= T2f) {                    // survivors <= SEL*CPT
                const int p = atomicAdd(&fcnt, 1);
                fD[p] = flipf(dist);
                fJ[p] = (unsigned short)j;
            }
        }
        __syncthreads();
        const int M2 = fcnt;
        for (int s2 = tid; s2 < M2; s2 += 256) {
            const unsigned dk = fD[s2];
            const unsigned short jk = fJ[s2];
            int rr = 0;
            for (int i2 = 0; i2 < M2; ++i2) {
                const unsigned di = fD[i2];
                rr += (di < dk || (di == dk && fJ[i2] < jk)) ? 1 : 0;
            }
            if (rr >= 1 && rr < SEL)
                outIdx[(size_t)(b * nRows + row0 + qq) * (SEL - 1) + (rr - 1)]
                    = (int)jk;
        }
        __syncthreads();                          // before next pool reuse
    }
}

// conv v4: wave-per-vertex with optional VPW vertices per wave (VPW=2 for
// small oc so no lanes idle); VC-channel vectorized gathers; fma allowed.
template <int NT, int VC, int VPW = 1>
__global__ __launch_bounds__(NT) void conv_kernel(
    const int*    __restrict__ idx,   // (B, V, NN)
    const float4* __restrict__ vq,    // (B, vStride)
    int vStride, int V, int NN,
    const float* __restrict__ fout,   // (B, V, 2*oc) or nullptr
    int oc,
    const float* __restrict__ dirs,   // (3, oc)
    float* __restrict__ out,          // (B, V, oc)
    int do_relu)
{
    constexpr int NWAVE = NT / 64;
    constexpr int NV    = NWAVE * VPW;      // vertices per block
    __shared__ float dnx[NV][64], dny[NV][64], dnz[NV][64];
    __shared__ int   nb[NV][64];

    for (int t = threadIdx.x; t < NV * 64; t += NT) {
        const int vloc = t >> 6, lane2 = t & 63;
        if (lane2 < NN) {
            const int vi = blockIdx.x * NV + vloc;   // b*V + i
            const int b  = vi / V;
            const int i  = vi % V;
            const int j  = idx[(size_t)vi * NN + lane2];
            nb[vloc][lane2] = j;
            const float4 ci = vq[(size_t)b * vStride + i];
            const float4 cj = vq[(size_t)b * vStride + j];
            const float dx = cj.x - ci.x;
            const float dy = cj.y - ci.y;
            const float dz = cj.z - ci.z;
            const float n  = sqrtf((dx * dx + dy * dy) + dz * dz);
            const float dnv = fmaxf(n, 1e-12f);
            dnx[vloc][lane2] = dx / dnv;
            dny[vloc][lane2] = dy / dnv;
            dnz[vloc][lane2] = dz / dnv;
        }
    }
    __syncthreads();

    const int w     = threadIdx.x >> 6;
    const int lane  = threadIdx.x & 63;
    const int sub   = (VPW == 1) ? 0 : (lane >> 5);
    const int laneC = (VPW == 1) ? lane : (lane & 31);
    const int vloc  = w * VPW + sub;
    const int vi    = blockIdx.x * NV + vloc;   // b*V + i
    const int b     = vi / V;

    const int c0 = blockIdx.y * ((64 / VPW) * VC) + laneC * VC;
    if (c0 >= oc) return;

    float d0[VC], d1[VC], d2[VC], fcen[VC], m[VC];
#pragma unroll
    for (int k = 0; k < VC; ++k) {
        const float a  = dirs[c0 + k];
        const float bb = dirs[oc + c0 + k];
        const float cc = dirs[2 * oc + c0 + k];
        const float nd = sqrtf((a * a + bb * bb) + cc * cc);
        const float dc = fmaxf(nd, 1e-12f);
        d0[k] = a / dc; d1[k] = bb / dc; d2[k] = cc / dc;
        fcen[k] = 0.f;
        m[k] = -INFINITY;
    }
    const float* fsup = nullptr;
    if (fout) {
        fsup = fout + (size_t)b * V * (2 * oc) + oc;
        load_vec<VC>(fcen, &fout[(size_t)vi * (2 * oc) + c0]);
    }

    constexpr int BN = (VC >= 4) ? 5 : 10;   // BN divides 50
    for (int n0 = 0; n0 < 50; n0 += BN) {
        float fs[BN][VC];
        if (fsup) {
#pragma unroll
            for (int u = 0; u < BN; ++u)
                load_vec<VC>(fs[u], &fsup[(size_t)nb[vloc][n0 + u] * (2 * oc) + c0]);
        } else {
#pragma unroll
            for (int u = 0; u < BN; ++u)
#pragma unroll
                for (int k = 0; k < VC; ++k) fs[u][k] = 1.f;
        }
#pragma unroll
        for (int u = 0; u < BN; ++u) {
            const int n = n0 + u;
            const float ax = dnx[vloc][n], ay = dny[vloc][n], az = dnz[vloc][n];
#pragma unroll
            for (int k = 0; k < VC; ++k) {
                float th = (ax * d0[k] + ay * d1[k]) + az * d2[k];
                th = fmaxf(th, 0.f);
                m[k] = fmaxf(m[k], th * fs[u][k]);
            }
        }
    }
    float r[VC];
#pragma unroll
    for (int k = 0; k < VC; ++k) {
        r[k] = fcen[k] + m[k];
        if (do_relu) r[k] = fmaxf(r[k], 0.f);
    }
    store_vec<VC>(&out[(size_t)vi * oc + c0], r);
}

// out(M,N) = A(M,K) @ W(K,N) + bias(N). 64x64 tile, BK=32, 256 threads,
// 4x4 per thread.
__global__ __launch_bounds__(256) void gemm_tiled(
    const float* __restrict__ A, const float* __restrict__ W,
    const float* __restrict__ bias, float* __restrict__ out,
    int M, int K, int N)
{
    __shared__ float As[32][68];
    __shared__ float Bs[32][64];
    const int tid = threadIdx.x;
    const int tx = tid & 15, ty = tid >> 4;
    const int r0 = blockIdx.x * 64;
    const int c0 = blockIdx.y * 64;

    const float4 bv = *(const float4*)&bias[c0 + tx * 4];
    float acc[4][4];
#pragma unroll
    for (int i = 0; i < 4; ++i) {
        acc[i][0] = bv.x; acc[i][1] = bv.y; acc[i][2] = bv.z; acc[i][3] = bv.w;
    }

    const int rowA = tid >> 2;
    const int ca4  = tid & 3;
    const int rowB = tid >> 4;
    const int cb4  = tid & 15;

    for (int k0 = 0; k0 < K; k0 += 32) {
        const float4 a0 = *(const float4*)&A[(size_t)(r0 + rowA) * K + k0 + ca4 * 4];
        const float4 a1 = *(const float4*)&A[(size_t)(r0 + rowA) * K + k0 + (ca4 + 4) * 4];
        const float4 b0 = *(const float4*)&W[(size_t)(k0 + rowB) * N + c0 + cb4 * 4];
        const float4 b1 = *(const float4*)&W[(size_t)(k0 + rowB + 16) * N + c0 + cb4 * 4];
        __syncthreads();
        As[ca4 * 4 + 0][rowA] = a0.x;
        As[ca4 * 4 + 1][rowA] = a0.y;
        As[ca4 * 4 + 2][rowA] = a0.z;
        As[ca4 * 4 + 3][rowA] = a0.w;
        As[ca4 * 4 + 16][rowA] = a1.x;
        As[ca4 * 4 + 17][rowA] = a1.y;
        As[ca4 * 4 + 18][rowA] = a1.z;
        As[ca4 * 4 + 19][rowA] = a1.w;
        *(float4*)&Bs[rowB][cb4 * 4]      = b0;
        *(float4*)&Bs[rowB + 16][cb4 * 4] = b1;
        __syncthreads();
#pragma unroll
        for (int kk = 0; kk < 32; ++kk) {
            const float4 av = *(const float4*)&As[kk][ty * 4];
            const float4 wv = *(const float4*)&Bs[kk][tx * 4];
            acc[0][0] += av.x * wv.x; acc[0][1] += av.x * wv.y;
            acc[0][2] += av.x * wv.z; acc[0][3] += av.x * wv.w;
            acc[1][0] += av.y * wv.x; acc[1][1] += av.y * wv.y;
            acc[1][2] += av.y * wv.z; acc[1][3] += av.y * wv.w;
            acc[2][0] += av.z * wv.x; acc[2][1] += av.z * wv.y;
            acc[2][2] += av.z * wv.z; acc[2][3] += av.z * wv.w;
            acc[3][0] += av.w * wv.x; acc[3][1] += av.w * wv.y;
            acc[3][2] += av.w * wv.z; acc[3][3] += av.w * wv.w;
        }
    }
#pragma unroll
    for (int i = 0; i < 4; ++i) {
        float4 o;
        o.x = acc[i][0]; o.y = acc[i][1]; o.z = acc[i][2]; o.w = acc[i][3];
        *(float4*)&out[(size_t)(r0 + ty * 4 + i) * N + c0 + tx * 4] = o;
    }
}

// flat grid: one thread per (b, i, c). pooled = max over first-4 of 50-NN row.
__global__ __launch_bounds__(256) void pool_max(
    const int* __restrict__ idxNN, int nnStride, const float* __restrict__ fm,
    int Vin, int pn, int C, float* __restrict__ out)
{
    const int t  = blockIdx.x * 256 + threadIdx.x;
    const int c  = t % C;
    const int bi = t / C;            // b*pn + i
    const int b  = bi / pn;
    const int i  = bi % pn;
    const int* r = idxNN + (size_t)(b * Vin + i) * nnStride;
    const int j0 = r[0], j1 = r[1], j2 = r[2], j3 = r[3];
    float m = fm[((size_t)b * Vin + j0) * C + c];
    m = fmaxf(m, fm[((size_t)b * Vin + j1) * C + c]);
    m = fmaxf(m, fm[((size_t)b * Vin + j2) * C + c]);
    m = fmaxf(m, fm[((size_t)b * Vin + j3) * C + c]);
    out[(size_t)bi * C + c] = m;
}

// partial column max over a chunk of rows. grid (C/256, B, nChunk).
__global__ __launch_bounds__(256) void colmax_part(
    const float* __restrict__ fm, int V, int C, int rowsPerChunk,
    float* __restrict__ part)
{
    const int b = blockIdx.y, chunk = blockIdx.z;
    const int nChunk = gridDim.z;
    const int c = blockIdx.x * 256 + threadIdx.x;
    const int i0 = chunk * rowsPerChunk;
    float m = -INFINITY;
    for (int i = i0; i < i0 + rowsPerChunk; ++i)
        m = fmaxf(m, fm[((size_t)b * V + i) * C + c]);
    part[((size_t)b * nChunk + chunk) * C + c] = m;
}

// out[b, :256] = (max-merge of partials)[b, :1024] @ W(1024,256) + bias
__global__ __launch_bounds__(256) void fc_kernel(
    const float* __restrict__ part, const float* __restrict__ W,
    const float* __restrict__ bias, float* __restrict__ out, int nChunk)
{
    __shared__ float f[1024];
    const int b = blockIdx.x, tid = threadIdx.x;
    for (int k = tid; k < 1024; k += 256) {
        float m = part[((size_t)b * nChunk) * 1024 + k];
        for (int ch = 1; ch < nChunk; ++ch)
            m = fmaxf(m, part[((size_t)b * nChunk + ch) * 1024 + k]);
        f[k] = m;
    }
    __syncthreads();
    float acc = bias[tid];
    for (int k = 0; k < 1024; ++k) acc += f[k] * W[(size_t)k * 256 + tid];
    out[(size_t)b * 256 + tid] = acc;
}

extern "C" void kernel_launch(void* const* d_in, const int* in_sizes, int n_in,
                              void* d_out, int out_size, void* d_ws, size_t ws_size,
                              hipStream_t stream) {
    const float* verts = (const float*)d_in[0];
    const float* dir0  = (const float*)d_in[1];
    const float* w1 = (const float*)d_in[2];
    const float* b1 = (const float*)d_in[3];
    const float* d1 = (const float*)d_in[4];
    const float* w2 = (const float*)d_in[5];
    const float* b2 = (const float*)d_in[6];
    const float* d2 = (const float*)d_in[7];
    const float* w3 = (const float*)d_in[8];
    const float* b3 = (const float*)d_in[9];
    const float* d3 = (const float*)d_in[10];
    const float* w4 = (const float*)d_in[11];
    const float* b4 = (const float*)d_in[12];
    const float* d4 = (const float*)d_in[13];
    const float* fcw = (const float*)d_in[14];
    const float* fcb = (const float*)d_in[15];

    const int B = 2, V1 = 8192, V2 = 2048, V3 = 512, NN = 50;

    char* ws = (char*)d_ws;
    float*  arena1 = (float*)(ws + 0);          //  8,388,608 : fout1 / fout3 / fout4
    float*  arena2 = (float*)(ws + 8388608);    //  4,194,304 : fm1 / fm3 / fm4
    float*  arena3 = (float*)(ws + 12582912);   //  4,194,304 : fout2
    int*    arena4 = (int*)  (ws + 16777216);   //  3,276,800 : idxA / idxB / idxC
    float*  arena5 = (float*)(ws + 20054016);   //  2,097,152 : fm0 / fm2
    float*  arena6 = (float*)(ws + 22151168);   //  1,048,576 : fm1p / fm3p
    float*  part   = (float*)(ws + 23265280);   //     65,536 : colmax partials
    float4* vq     = (float4*)(ws + 23330816);  //    262,144 : packed {x,y,z,q}

    precompute_vq<<<(B * V1 + 255) / 256, 256, 0, stream>>>(verts, vq, B * V1);

    // ---- Stage 1 (V=8192) ----
    int* idxA = arena4;
    knn_select<32, 8, 51, 20><<<B * V1 / 8, 256, 0, stream>>>(vq, V1, V1, idxA);

    float* fm0 = arena5;
    conv_kernel<256, 1, 2><<<dim3(B * V1 / 8, 1), 256, 0, stream>>>(
        idxA, vq, V1, V1, NN, nullptr, 32, dir0, fm0, 1);
    float* fout1 = arena1;
    gemm_tiled<<<dim3(B * V1 / 64, 128 / 64), 256, 0, stream>>>(
        fm0, w1, b1, fout1, B * V1, 32, 128);
    float* fm1 = arena2;
    conv_kernel<256, 1><<<dim3(B * V1 / 4, 1), 256, 0, stream>>>(
        idxA, vq, V1, V1, NN, fout1, 64, d1, fm1, 1);
    // pool 8192 -> 2048 : 4-NN = first 4 of the 50-NN rows
    float* fm1p = arena6;
    pool_max<<<B * V2 * 64 / 256, 256, 0, stream>>>(idxA, NN, fm1, V1, V2, 64, fm1p);

    // ---- Stage 2 (V=2048) ----
    int* idxB = arena4;
    knn_select<8, 2, 51, 20><<<B * V2 / 8, 256, 0, stream>>>(vq, V1, V2, idxB);
    float* fout2 = arena3;
    gemm_tiled<<<dim3(B * V2 / 64, 256 / 64), 256, 0, stream>>>(
        fm1p, w2, b2, fout2, B * V2, 64, 256);
    float* fm2 = arena5;
    conv_kernel<256, 2><<<dim3(B * V2 / 4, 1), 256, 0, stream>>>(
        idxB, vq, V1, V2, NN, fout2, 128, d2, fm2, 1);
    float* fout3 = arena1;
    gemm_tiled<<<dim3(B * V2 / 64, 512 / 64), 256, 0, stream>>>(
        fm2, w3, b3, fout3, B * V2, 128, 512);
    float* fm3 = arena2;
    conv_kernel<256, 4><<<dim3(B * V2 / 4, 1), 256, 0, stream>>>(
        idxB, vq, V1, V2, NN, fout3, 256, d3, fm3, 1);
    // pool 2048 -> 512 : 4-NN = first 4 of the 50-NN rows
    float* fm3p = arena6;
    pool_max<<<B * V3 * 256 / 256, 256, 0, stream>>>(idxB, NN, fm3, V2, V3, 256, fm3p);

    // ---- Stage 3 (V=512) ----
    int* idxC = arena4;
    knn_select<2, 2, 51, 48><<<B * V3 / 8, 256, 0, stream>>>(vq, V1, V3, idxC);
    float* fout4 = arena1;
    gemm_tiled<<<dim3(B * V3 / 64, 2048 / 64), 256, 0, stream>>>(
        fm3p, w4, b4, fout4, B * V3, 256, 2048);
    float* fm4 = arena2;
    // oc=1024: 4 channel-chunks of 256 across grid.y
    conv_kernel<256, 4><<<dim3(B * V3 / 4, 4), 256, 0, stream>>>(
        idxC, vq, V1, V3, NN, fout4, 1024, d4, fm4, 0);
    // ---- Head ----
    colmax_part<<<dim3(1024 / 256, B, 8), 256, 0, stream>>>(fm4, V3, 1024, V3 / 8, part);
    fc_kernel<<<B, 256, 0, stream>>>(part, fcw, fcb, (float*)d_out, 8);
}

// Round 19
// 328.898 us; speedup vs baseline: 1.0354x; 1.0354x over previous
//
#include <hip/hip_runtime.h>
#include <cmath>

// ---------------------------------------------------------------------------
// PointCloudFeatureExtractor — full pipeline port (fp32).
// Round 19: R18 with the SECOND overflow fixed: fout4 -> arena1 (8 MB; fout3
//           dead after conv3). Full buffer-size audit in launch comments.
//           knn = R15-exact. pool fused into gemm2/gemm4.
// ---------------------------------------------------------------------------

__device__ __forceinline__ unsigned flipf(float f) {
    unsigned u = __float_as_uint(f);
    return (u & 0x80000000u) ? ~u : (u | 0x80000000u);
}
__device__ __forceinline__ float unflip(unsigned u) {
    unsigned r = (u & 0x80000000u) ? (u & 0x7fffffffu) : ~u;
    return __uint_as_float(r);
}
__device__ __forceinline__ unsigned umin2(unsigned a, unsigned b) {
    return a < b ? a : b;
}

template <int VC>
__device__ __forceinline__ void load_vec(float* d, const float* p) {
    if constexpr (VC == 1) { d[0] = p[0]; }
    else if constexpr (VC == 2) { const float2 t = *(const float2*)p; d[0] = t.x; d[1] = t.y; }
    else { const float4 t = *(const float4*)p; d[0] = t.x; d[1] = t.y; d[2] = t.z; d[3] = t.w; }
}
template <int VC>
__device__ __forceinline__ void store_vec(float* p, const float* d) {
    if constexpr (VC == 1) { p[0] = d[0]; }
    else if constexpr (VC == 2) { float2 t; t.x = d[0]; t.y = d[1]; *(float2*)p = t; }
    else { float4 t; t.x = d[0]; t.y = d[1]; t.z = d[2]; t.w = d[3]; *(float4*)p = t; }
}

__device__ __forceinline__ float4 max4(float4 a, float4 b) {
    float4 r;
    r.x = fmaxf(a.x, b.x); r.y = fmaxf(a.y, b.y);
    r.z = fmaxf(a.z, b.z); r.w = fmaxf(a.w, b.w);
    return r;
}

// vq[i] = {x, y, z, (x*x+y*y)+z*z}  (exact op order of the distance formula)
__global__ __launch_bounds__(256) void precompute_vq(
    const float* __restrict__ v, float4* __restrict__ vq, int n)
{
#pragma clang fp contract(off)
    const int i = blockIdx.x * 256 + threadIdx.x;
    if (i < n) {
        const float x = v[i * 3 + 0];
        const float y = v[i * 3 + 1];
        const float z = v[i * 3 + 2];
        float4 o; o.x = x; o.y = y; o.z = z; o.w = (x * x + y * y) + z * z;
        vq[i] = o;
    }
}

// kNN v13 (R15 exact — best measured): QPB=8 queries/block, sampled pass-1
// single-pass estimator, PF-pipelined full pass-2 extraction, M>=SEL
// exactness check, register-cached final ranking, rank-then-fallback with
// fallback buffers aliasing bufq. Distances bit-identical to round-1.
template <int CPT, int SMP, int SEL, int EST, int QPB = 8, int CAPQ = 160>
__global__ __launch_bounds__(256, 4) void knn_select(
    const float4* __restrict__ vq, int vStride, int nRows,
    int* __restrict__ outIdx)
{
#pragma clang fp contract(off)
    const int tid  = threadIdx.x;
    const int bpb  = nRows / QPB;
    const int b    = blockIdx.x / bpb;
    const int row0 = (blockIdx.x % bpb) * QPB;
    const float4* vb = vq + (size_t)b * vStride;

    float nx[QPB], ny[QPB], nz[QPB], qw[QPB];
#pragma unroll
    for (int qq = 0; qq < QPB; ++qq) {
        const float4 p = vb[row0 + qq];
        nx[qq] = p.x * -2.0f; ny[qq] = p.y * -2.0f; nz[qq] = p.z * -2.0f;
        qw[qq] = p.w;
    }

    // ---- pass 1 (sampled): per-thread min per query over SMP candidates ----
    float mn[QPB];
#pragma unroll
    for (int qq = 0; qq < QPB; ++qq) mn[qq] = INFINITY;
#pragma unroll
    for (int s = 0; s < SMP; ++s) {
        const float4 c = vb[tid + (s << 8)];
#pragma unroll
        for (int qq = 0; qq < QPB; ++qq) {
            const float t0 = (nx[qq] * c.x + ny[qq] * c.y) + nz[qq] * c.z;
            const float dist = (t0 + c.w) + qw[qq];
            mn[qq] = fminf(mn[qq], dist);
        }
    }

    constexpr int POOLB = (QPB * CAPQ * 8 > CPT * SEL * 6) ? QPB * CAPQ * 8
                                                           : CPT * SEL * 6;
    __shared__ unsigned hmin[QPB][256];
    __shared__ __align__(16) char poolmem[POOLB];
    __shared__ unsigned Ts[QPB];
    __shared__ int cnt[QPB];
    __shared__ unsigned T2_s;
    __shared__ int fcnt;
    typedef unsigned long long u64row[CAPQ];
    u64row* bufq = (u64row*)poolmem;

#pragma unroll
    for (int qq = 0; qq < QPB; ++qq) hmin[qq][tid] = flipf(mn[qq]);
    if (tid < QPB) { Ts[tid] = 0u; cnt[tid] = 0; }
    __syncthreads();

    // ---- estimator: group g (32 thr) builds 64 combined minima in-place,
    //      then ranks BOTH its values in one 64-read sweep.
    {
        const int g = tid >> 5, l = tid & 31;
#pragma unroll
        for (int hh = 0; hh < 2; ++hh) {
            const int i = l + hh * 32;
            unsigned cm = hmin[g][i];
            cm = umin2(cm, hmin[g][i + 64]);
            cm = umin2(cm, hmin[g][i + 128]);
            cm = umin2(cm, hmin[g][i + 192]);
            hmin[g][i] = cm;
        }
        const unsigned vv0 = hmin[g][l];
        const unsigned vv1 = hmin[g][l + 32];
        int r0 = 0, r1 = 0;
#pragma unroll 8
        for (int k = 0; k < 64; ++k) {
            const unsigned h = hmin[g][k];
            r0 += (h < vv0) ? 1 : 0;
            r1 += (h < vv1) ? 1 : 0;
        }
        if (r0 < EST) atomicMax(&Ts[g], vv0);
        if (r1 < EST) atomicMax(&Ts[g], vv1);
    }
    __syncthreads();

    float Tf[QPB];
#pragma unroll
    for (int qq = 0; qq < QPB; ++qq) Tf[qq] = unflip(Ts[qq]);

    // ---- pass 2 (full): pipelined extraction ----
    {
        constexpr int PF = (CPT < 4) ? CPT : 4;
        float4 cbuf[PF];
#pragma unroll
        for (int p = 0; p < PF; ++p) cbuf[p] = vb[tid + (p << 8)];
        for (int s0 = 0; s0 < CPT; s0 += PF) {
            float4 cur[PF];
#pragma unroll
            for (int p = 0; p < PF; ++p) cur[p] = cbuf[p];
            if (s0 + PF < CPT) {
#pragma unroll
                for (int p = 0; p < PF; ++p)
                    cbuf[p] = vb[tid + ((s0 + PF + p) << 8)];
            }
#pragma unroll
            for (int p = 0; p < PF; ++p) {
                const int j = tid + ((s0 + p) << 8);
                const float4 c = cur[p];
#pragma unroll
                for (int qq = 0; qq < QPB; ++qq) {
                    const float t0 = (nx[qq] * c.x + ny[qq] * c.y) + nz[qq] * c.z;
                    const float dist = (t0 + c.w) + qw[qq];
                    if (dist <= Tf[qq]) {
                        const int p2 = atomicAdd(&cnt[qq], 1);
                        if (p2 < CAPQ)
                            bufq[qq][p2] =
                                (((unsigned long long)flipf(dist)) << 32)
                                | (unsigned)j;
                    }
                }
            }
        }
    }
    __syncthreads();

    // ---- normal ranking FIRST (register-cached; one bufq sweep) ----
    {
        const int g = tid >> 5, i = tid & 31;
        const int M = cnt[g];
        if (M >= SEL && M <= CAPQ) {
            constexpr int KMAX = (CAPQ + 31) / 32;
            unsigned long long myk[KMAX];
            int rr[KMAX];
#pragma unroll
            for (int t = 0; t < KMAX; ++t) {
                const int s2 = i + t * 32;
                myk[t] = (s2 < M) ? bufq[g][s2] : ~0ull;  // sentinel: rank>=SEL
                rr[t] = 0;
            }
            for (int i2 = 0; i2 < M; ++i2) {
                const unsigned long long k2 = bufq[g][i2];
#pragma unroll
                for (int t = 0; t < KMAX; ++t) rr[t] += (k2 < myk[t]) ? 1 : 0;
            }
#pragma unroll
            for (int t = 0; t < KMAX; ++t) {
                if (rr[t] >= 1 && rr[t] < SEL)
                    outIdx[(size_t)(b * nRows + row0 + g) * (SEL - 1) + (rr[t] - 1)]
                        = (int)(myk[t] & 0xffffffffu);
            }
        }
    }
    __syncthreads();

    // ---- rare provable fallback, serialized per bad query; reuses pool ----
    for (int qq = 0; qq < QPB; ++qq) {
        const int M = cnt[qq];
        if (M >= SEL && M <= CAPQ) continue;      // block-uniform
        unsigned* fD = (unsigned*)poolmem;
        unsigned short* fJ = (unsigned short*)(poolmem + CPT * SEL * 4);
        {
            float fm = INFINITY;
#pragma unroll 2
            for (int s = 0; s < CPT; ++s) {
                const float4 c = vb[tid + (s << 8)];
                const float t0 = (nx[qq] * c.x + ny[qq] * c.y) + nz[qq] * c.z;
                const float dist = (t0 + c.w) + qw[qq];
                fm = fminf(fm, dist);
            }
            hmin[qq][tid] = flipf(fm);
        }
        if (tid == 0) { T2_s = 0u; fcnt = 0; }
        __syncthreads();
        {
            const unsigned vv = hmin[qq][tid];
            int r = 0;
            for (int k = 0; k < 256; ++k) r += (hmin[qq][k] < vv) ? 1 : 0;
            if (r < SEL) atomicMax(&T2_s, vv);    // >= SEL keys <= T2
        }
        __syncthreads();
        const float T2f = unflip(T2_s);
#pragma unroll 2
        for (int s = 0; s < CPT; ++s) {
            const int j = tid + (s << 8);
            const float4 c = vb[j];
            const float t0 = (nx[qq] * c.x + ny[qq] * c.y) + nz[qq] * c.z;
            const float dist = (t0 + c.w) + qw[qq];
            if (dist <= T2f) {                    // survivors <= SEL*CPT
                const int p = atomicAdd(&fcnt, 1);
                fD[p] = flipf(dist);
                fJ[p] = (unsigned short)j;
            }
        }
        __syncthreads();
        const int M2 = fcnt;
        for (int s2 = tid; s2 < M2; s2 += 256) {
            const unsigned dk = fD[s2];
            const unsigned short jk = fJ[s2];
            int rr = 0;
            for (int i2 = 0; i2 < M2; ++i2) {
                const unsigned di = fD[i2];
                rr += (di < dk || (di == dk && fJ[i2] < jk)) ? 1 : 0;
            }
            if (rr >= 1 && rr < SEL)
                outIdx[(size_t)(b * nRows + row0 + qq) * (SEL - 1) + (rr - 1)]
                    = (int)jk;
        }
        __syncthreads();                          // before next pool reuse
    }
}

// conv v4: wave-per-vertex with optional VPW vertices per wave; VC-channel
// vectorized gathers; fma allowed (bf16-rounded comparison absorbs ulps).
template <int NT, int VC, int VPW = 1>
__global__ __launch_bounds__(NT) void conv_kernel(
    const int*    __restrict__ idx,   // (B, V, NN)
    const float4* __restrict__ vq,    // (B, vStride)
    int vStride, int V, int NN,
    const float* __restrict__ fout,   // (B, V, 2*oc) or nullptr
    int oc,
    const float* __restrict__ dirs,   // (3, oc)
    float* __restrict__ out,          // (B, V, oc)
    int do_relu)
{
    constexpr int NWAVE = NT / 64;
    constexpr int NV    = NWAVE * VPW;      // vertices per block
    __shared__ float dnx[NV][64], dny[NV][64], dnz[NV][64];
    __shared__ int   nb[NV][64];

    for (int t = threadIdx.x; t < NV * 64; t += NT) {
        const int vloc = t >> 6, lane2 = t & 63;
        if (lane2 < NN) {
            const int vi = blockIdx.x * NV + vloc;   // b*V + i
            const int b  = vi / V;
            const int i  = vi % V;
            const int j  = idx[(size_t)vi * NN + lane2];
            nb[vloc][lane2] = j;
            const float4 ci = vq[(size_t)b * vStride + i];
            const float4 cj = vq[(size_t)b * vStride + j];
            const float dx = cj.x - ci.x;
            const float dy = cj.y - ci.y;
            const float dz = cj.z - ci.z;
            const float n  = sqrtf((dx * dx + dy * dy) + dz * dz);
            const float dnv = fmaxf(n, 1e-12f);
            dnx[vloc][lane2] = dx / dnv;
            dny[vloc][lane2] = dy / dnv;
            dnz[vloc][lane2] = dz / dnv;
        }
    }
    __syncthreads();

    const int w     = threadIdx.x >> 6;
    const int lane  = threadIdx.x & 63;
    const int sub   = (VPW == 1) ? 0 : (lane >> 5);
    const int laneC = (VPW == 1) ? lane : (lane & 31);
    const int vloc  = w * VPW + sub;
    const int vi    = blockIdx.x * NV + vloc;   // b*V + i
    const int b     = vi / V;

    const int c0 = blockIdx.y * ((64 / VPW) * VC) + laneC * VC;
    if (c0 >= oc) return;

    float d0[VC], d1[VC], d2[VC], fcen[VC], m[VC];
#pragma unroll
    for (int k = 0; k < VC; ++k) {
        const float a  = dirs[c0 + k];
        const float bb = dirs[oc + c0 + k];
        const float cc = dirs[2 * oc + c0 + k];
        const float nd = sqrtf((a * a + bb * bb) + cc * cc);
        const float dc = fmaxf(nd, 1e-12f);
        d0[k] = a / dc; d1[k] = bb / dc; d2[k] = cc / dc;
        fcen[k] = 0.f;
        m[k] = -INFINITY;
    }
    const float* fsup = nullptr;
    if (fout) {
        fsup = fout + (size_t)b * V * (2 * oc) + oc;
        load_vec<VC>(fcen, &fout[(size_t)vi * (2 * oc) + c0]);
    }

    constexpr int BN = (VC >= 4) ? 5 : 10;   // BN divides 50
    for (int n0 = 0; n0 < 50; n0 += BN) {
        float fs[BN][VC];
        if (fsup) {
#pragma unroll
            for (int u = 0; u < BN; ++u)
                load_vec<VC>(fs[u], &fsup[(size_t)nb[vloc][n0 + u] * (2 * oc) + c0]);
        } else {
#pragma unroll
            for (int u = 0; u < BN; ++u)
#pragma unroll
                for (int k = 0; k < VC; ++k) fs[u][k] = 1.f;
        }
#pragma unroll
        for (int u = 0; u < BN; ++u) {
            const int n = n0 + u;
            const float ax = dnx[vloc][n], ay = dny[vloc][n], az = dnz[vloc][n];
#pragma unroll
            for (int k = 0; k < VC; ++k) {
                float th = (ax * d0[k] + ay * d1[k]) + az * d2[k];
                th = fmaxf(th, 0.f);
                m[k] = fmaxf(m[k], th * fs[u][k]);
            }
        }
    }
    float r[VC];
#pragma unroll
    for (int k = 0; k < VC; ++k) {
        r[k] = fcen[k] + m[k];
        if (do_relu) r[k] = fmaxf(r[k], 0.f);
    }
    store_vec<VC>(&out[(size_t)vi * oc + c0], r);
}

// out(M,N) = A(M,K) @ W(K,N) + bias(N). 64x64 tile, BK=32, 256 threads,
// 4x4 per thread.
__global__ __launch_bounds__(256) void gemm_tiled(
    const float* __restrict__ A, const float* __restrict__ W,
    const float* __restrict__ bias, float* __restrict__ out,
    int M, int K, int N)
{
    __shared__ float As[32][68];
    __shared__ float Bs[32][64];
    const int tid = threadIdx.x;
    const int tx = tid & 15, ty = tid >> 4;
    const int r0 = blockIdx.x * 64;
    const int c0 = blockIdx.y * 64;

    const float4 bv = *(const float4*)&bias[c0 + tx * 4];
    float acc[4][4];
#pragma unroll
    for (int i = 0; i < 4; ++i) {
        acc[i][0] = bv.x; acc[i][1] = bv.y; acc[i][2] = bv.z; acc[i][3] = bv.w;
    }

    const int rowA = tid >> 2;
    const int ca4  = tid & 3;
    const int rowB = tid >> 4;
    const int cb4  = tid & 15;

    for (int k0 = 0; k0 < K; k0 += 32) {
        const float4 a0 = *(const float4*)&A[(size_t)(r0 + rowA) * K + k0 + ca4 * 4];
        const float4 a1 = *(const float4*)&A[(size_t)(r0 + rowA) * K + k0 + (ca4 + 4) * 4];
        const float4 b0 = *(const float4*)&W[(size_t)(k0 + rowB) * N + c0 + cb4 * 4];
        const float4 b1 = *(const float4*)&W[(size_t)(k0 + rowB + 16) * N + c0 + cb4 * 4];
        __syncthreads();
        As[ca4 * 4 + 0][rowA] = a0.x;
        As[ca4 * 4 + 1][rowA] = a0.y;
        As[ca4 * 4 + 2][rowA] = a0.z;
        As[ca4 * 4 + 3][rowA] = a0.w;
        As[ca4 * 4 + 16][rowA] = a1.x;
        As[ca4 * 4 + 17][rowA] = a1.y;
        As[ca4 * 4 + 18][rowA] = a1.z;
        As[ca4 * 4 + 19][rowA] = a1.w;
        *(float4*)&Bs[rowB][cb4 * 4]      = b0;
        *(float4*)&Bs[rowB + 16][cb4 * 4] = b1;
        __syncthreads();
#pragma unroll
        for (int kk = 0; kk < 32; ++kk) {
            const float4 av = *(const float4*)&As[kk][ty * 4];
            const float4 wv = *(const float4*)&Bs[kk][tx * 4];
            acc[0][0] += av.x * wv.x; acc[0][1] += av.x * wv.y;
            acc[0][2] += av.x * wv.z; acc[0][3] += av.x * wv.w;
            acc[1][0] += av.y * wv.x; acc[1][1] += av.y * wv.y;
            acc[1][2] += av.y * wv.z; acc[1][3] += av.y * wv.w;
            acc[2][0] += av.z * wv.x; acc[2][1] += av.z * wv.y;
            acc[2][2] += av.z * wv.z; acc[2][3] += av.z * wv.w;
            acc[3][0] += av.w * wv.x; acc[3][1] += av.w * wv.y;
            acc[3][2] += av.w * wv.z; acc[3][3] += av.w * wv.w;
        }
    }
#pragma unroll
    for (int i = 0; i < 4; ++i) {
        float4 o;
        o.x = acc[i][0]; o.y = acc[i][1]; o.z = acc[i][2]; o.w = acc[i][3];
        *(float4*)&out[(size_t)(r0 + ty * 4 + i) * N + c0 + tx * 4] = o;
    }
}

// Fused pool+GEMM: A-rows are the 4-neighbor max of Afm rows (pool(rate=4)
// semantics, identical fmax order as the old pool_max kernel).
__global__ __launch_bounds__(256) void gemm_pool_tiled(
    const float* __restrict__ Afm,    // (B, Vin, K)
    const int*   __restrict__ idxNN,  // (B, Vin, nnStride)
    int nnStride, int Vin, int pn,
    const float* __restrict__ W,
    const float* __restrict__ bias, float* __restrict__ out,
    int M, int K, int N)
{
    __shared__ float As[32][68];
    __shared__ float Bs[32][64];
    const int tid = threadIdx.x;
    const int tx = tid & 15, ty = tid >> 4;
    const int r0 = blockIdx.x * 64;
    const int c0 = blockIdx.y * 64;

    const float4 bv = *(const float4*)&bias[c0 + tx * 4];
    float acc[4][4];
#pragma unroll
    for (int i = 0; i < 4; ++i) {
        acc[i][0] = bv.x; acc[i][1] = bv.y; acc[i][2] = bv.z; acc[i][3] = bv.w;
    }

    const int rowA = tid >> 2;
    const int ca4  = tid & 3;
    const int rowB = tid >> 4;
    const int cb4  = tid & 15;

    const int prow = r0 + rowA;
    const int pb = prow / pn, pi = prow % pn;
    const int* rr = idxNN + (size_t)(pb * Vin + pi) * nnStride;
    const int j0 = rr[0], j1 = rr[1], j2 = rr[2], j3 = rr[3];
    const float* A0 = Afm + (size_t)(pb * Vin + j0) * K;
    const float* A1 = Afm + (size_t)(pb * Vin + j1) * K;
    const float* A2 = Afm + (size_t)(pb * Vin + j2) * K;
    const float* A3 = Afm + (size_t)(pb * Vin + j3) * K;

    for (int k0 = 0; k0 < K; k0 += 32) {
        const int ka = k0 + ca4 * 4, kb = k0 + (ca4 + 4) * 4;
        float4 a0 = *(const float4*)&A0[ka];
        a0 = max4(a0, *(const float4*)&A1[ka]);
        a0 = max4(a0, *(const float4*)&A2[ka]);
        a0 = max4(a0, *(const float4*)&A3[ka]);
        float4 a1 = *(const float4*)&A0[kb];
        a1 = max4(a1, *(const float4*)&A1[kb]);
        a1 = max4(a1, *(const float4*)&A2[kb]);
        a1 = max4(a1, *(const float4*)&A3[kb]);
        const float4 b0 = *(const float4*)&W[(size_t)(k0 + rowB) * N + c0 + cb4 * 4];
        const float4 b1 = *(const float4*)&W[(size_t)(k0 + rowB + 16) * N + c0 + cb4 * 4];
        __syncthreads();
        As[ca4 * 4 + 0][rowA] = a0.x;
        As[ca4 * 4 + 1][rowA] = a0.y;
        As[ca4 * 4 + 2][rowA] = a0.z;
        As[ca4 * 4 + 3][rowA] = a0.w;
        As[ca4 * 4 + 16][rowA] = a1.x;
        As[ca4 * 4 + 17][rowA] = a1.y;
        As[ca4 * 4 + 18][rowA] = a1.z;
        As[ca4 * 4 + 19][rowA] = a1.w;
        *(float4*)&Bs[rowB][cb4 * 4]      = b0;
        *(float4*)&Bs[rowB + 16][cb4 * 4] = b1;
        __syncthreads();
#pragma unroll
        for (int kk = 0; kk < 32; ++kk) {
            const float4 av = *(const float4*)&As[kk][ty * 4];
            const float4 wv = *(const float4*)&Bs[kk][tx * 4];
            acc[0][0] += av.x * wv.x; acc[0][1] += av.x * wv.y;
            acc[0][2] += av.x * wv.z; acc[0][3] += av.x * wv.w;
            acc[1][0] += av.y * wv.x; acc[1][1] += av.y * wv.y;
            acc[1][2] += av.y * wv.z; acc[1][3] += av.y * wv.w;
            acc[2][0] += av.z * wv.x; acc[2][1] += av.z * wv.y;
            acc[2][2] += av.z * wv.z; acc[2][3] += av.z * wv.w;
            acc[3][0] += av.w * wv.x; acc[3][1] += av.w * wv.y;
            acc[3][2] += av.w * wv.z; acc[3][3] += av.w * wv.w;
        }
    }
#pragma unroll
    for (int i = 0; i < 4; ++i) {
        float4 o;
        o.x = acc[i][0]; o.y = acc[i][1]; o.z = acc[i][2]; o.w = acc[i][3];
        *(float4*)&out[(size_t)(r0 + ty * 4 + i) * N + c0 + tx * 4] = o;
    }
}

// partial column max over a chunk of rows. grid (C/256, B, nChunk).
__global__ __launch_bounds__(256) void colmax_part(
    const float* __restrict__ fm, int V, int C, int rowsPerChunk,
    float* __restrict__ part)
{
    const int b = blockIdx.y, chunk = blockIdx.z;
    const int nChunk = gridDim.z;
    const int c = blockIdx.x * 256 + threadIdx.x;
    const int i0 = chunk * rowsPerChunk;
    float m = -INFINITY;
    for (int i = i0; i < i0 + rowsPerChunk; ++i)
        m = fmaxf(m, fm[((size_t)b * V + i) * C + c]);
    part[((size_t)b * nChunk + chunk) * C + c] = m;
}

// out[b, :256] = (max-merge of partials)[b, :1024] @ W(1024,256) + bias
__global__ __launch_bounds__(256) void fc_kernel(
    const float* __restrict__ part, const float* __restrict__ W,
    const float* __restrict__ bias, float* __restrict__ out, int nChunk)
{
    __shared__ float f[1024];
    const int b = blockIdx.x, tid = threadIdx.x;
    for (int k = tid; k < 1024; k += 256) {
        float m = part[((size_t)b * nChunk) * 1024 + k];
        for (int ch = 1; ch < nChunk; ++ch)
            m = fmaxf(m, part[((size_t)b * nChunk + ch) * 1024 + k]);
        f[k] = m;
    }
    __syncthreads();
    float acc = bias[tid];
    for (int k = 0; k < 1024; ++k) acc += f[k] * W[(size_t)k * 256 + tid];
    out[(size_t)b * 256 + tid] = acc;
}

extern "C" void kernel_launch(void* const* d_in, const int* in_sizes, int n_in,
                              void* d_out, int out_size, void* d_ws, size_t ws_size,
                              hipStream_t stream) {
    const float* verts = (const float*)d_in[0];
    const float* dir0  = (const float*)d_in[1];
    const float* w1 = (const float*)d_in[2];
    const float* b1 = (const float*)d_in[3];
    const float* d1 = (const float*)d_in[4];
    const float* w2 = (const float*)d_in[5];
    const float* b2 = (const float*)d_in[6];
    const float* d2 = (const float*)d_in[7];
    const float* w3 = (const float*)d_in[8];
    const float* b3 = (const float*)d_in[9];
    const float* d3 = (const float*)d_in[10];
    const float* w4 = (const float*)d_in[11];
    const float* b4 = (const float*)d_in[12];
    const float* d4 = (const float*)d_in[13];
    const float* fcw = (const float*)d_in[14];
    const float* fcb = (const float*)d_in[15];

    const int B = 2, V1 = 8192, V2 = 2048, V3 = 512, NN = 50;

    // Arena audit (bytes):
    //   arena1 (8,388,608): fout1 8MB -> fout3 8MB -> fout4 8MB  (serial)
    //   arena2 (4,194,304): fm1 2MB  -> fm3 2MB  -> fm4 4MB      (serial)
    //   arena3 (4,194,304): fout2 4MB                             (single)
    //   arena4 (3,276,800): idxA 3.125MB -> idxB .78MB -> idxC .2MB
    //   arena5 (2,097,152): fm0 1MB  -> fm2 1MB                   (serial)
    char* ws = (char*)d_ws;
    float*  arena1 = (float*)(ws + 0);
    float*  arena2 = (float*)(ws + 8388608);
    float*  arena3 = (float*)(ws + 12582912);
    int*    arena4 = (int*)  (ws + 16777216);
    float*  arena5 = (float*)(ws + 20054016);
    float*  part   = (float*)(ws + 23265280);   //  65,536 : colmax partials
    float4* vq     = (float4*)(ws + 23330816);  // 262,144 : packed {x,y,z,q}

    precompute_vq<<<(B * V1 + 255) / 256, 256, 0, stream>>>(verts, vq, B * V1);

    // ---- Stage 1 (V=8192) ----
    int* idxA = arena4;
    knn_select<32, 8, 51, 20><<<B * V1 / 8, 256, 0, stream>>>(vq, V1, V1, idxA);

    float* fm0 = arena5;
    conv_kernel<256, 1, 2><<<dim3(B * V1 / 8, 1), 256, 0, stream>>>(
        idxA, vq, V1, V1, NN, nullptr, 32, dir0, fm0, 1);
    float* fout1 = arena1;
    gemm_tiled<<<dim3(B * V1 / 64, 128 / 64), 256, 0, stream>>>(
        fm0, w1, b1, fout1, B * V1, 32, 128);
    float* fm1 = arena2;
    conv_kernel<256, 1><<<dim3(B * V1 / 4, 1), 256, 0, stream>>>(
        idxA, vq, V1, V1, NN, fout1, 64, d1, fm1, 1);

    // ---- Stage 2 (V=2048); pool(8192->2048) fused into gemm2's A-load ----
    float* fout2 = arena3;   // 4MB, fits exactly
    gemm_pool_tiled<<<dim3(B * V2 / 64, 256 / 64), 256, 0, stream>>>(
        fm1, idxA, NN, V1, V2, w2, b2, fout2, B * V2, 64, 256);
    int* idxB = arena4;   // launched after gemm2 (gemm2 reads idxA=arena4)
    knn_select<8, 2, 51, 20><<<B * V2 / 8, 256, 0, stream>>>(vq, V1, V2, idxB);
    float* fm2 = arena5;
    conv_kernel<256, 2><<<dim3(B * V2 / 4, 1), 256, 0, stream>>>(
        idxB, vq, V1, V2, NN, fout2, 128, d2, fm2, 1);
    float* fout3 = arena1;   // fout1 dead after conv1
    gemm_tiled<<<dim3(B * V2 / 64, 512 / 64), 256, 0, stream>>>(
        fm2, w3, b3, fout3, B * V2, 128, 512);
    float* fm3 = arena2;     // fm1 dead after gemm2
    conv_kernel<256, 4><<<dim3(B * V2 / 4, 1), 256, 0, stream>>>(
        idxB, vq, V1, V2, NN, fout3, 256, d3, fm3, 1);

    // ---- Stage 3 (V=512); pool(2048->512) fused into gemm4's A-load ----
    float* fout4 = arena1;   // 8MB needed; fout3 dead after conv3
    gemm_pool_tiled<<<dim3(B * V3 / 64, 2048 / 64), 256, 0, stream>>>(
        fm3, idxB, NN, V2, V3, w4, b4, fout4, B * V3, 256, 2048);
    int* idxC = arena4;   // launched after gemm4 (gemm4 reads idxB=arena4)
    knn_select<2, 2, 51, 48><<<B * V3 / 8, 256, 0, stream>>>(vq, V1, V3, idxC);
    float* fm4 = arena2;  // 4MB; fm3 dead after gemm4
    conv_kernel<256, 4><<<dim3(B * V3 / 4, 4), 256, 0, stream>>>(
        idxC, vq, V1, V3, NN, fout4, 1024, d4, fm4, 0);
    // ---- Head ----
    colmax_part<<<dim3(1024 / 256, B, 8), 256, 0, stream>>>(fm4, V3, 1024, V3 / 8, part);
    fc_kernel<<<B, 256, 0, stream>>>(part, fcw, fcb, (float*)d_out, 8);
}